// Round 1
// baseline (394.429 us; speedup 1.0000x reference)
//
#include <hip/hip_runtime.h>
#include <hip/hip_bf16.h>

// Problem constants (fixed by the reference)
#define LATENT 32
#define HID 64
#define NB 256          // batch (graphs)
#define NN 200000       // nodes
#define NE 1500000      // edges
#define TWOH 128        // 2*HID

// Output layout (flat floats in d_out)
#define OUT_NODE_OFF   0
#define OUT_EDGE_OFF   (NN * 4)                   // 800000
#define OUT_ENERGY_OFF (OUT_EDGE_OFF + NE * 3)    // 5300000
#define OUT_STRESS_OFF (OUT_ENERGY_OFF + NB * 2)  // 5300512

// Workspace layout (flat floats in d_ws)
#define WS_ZPROJ 0                      // [256][128]
#define WS_ZC    (WS_ZPROJ + NB*TWOH)   // [256][64]  z_proj @ nd1_w
#define WS_P1    (WS_ZC + NB*HID)       // [256][64]  z_proj @ ed1_w[0:128]
#define WS_P2    (WS_P1 + NB*HID)       // [256][64]  z_proj @ ed1_w[128:256]
#define WS_T4    (WS_P2 + NB*HID)       // [256][256][4] edge pair table (float4)

// ---------------------------------------------------------------------------
// Kernel 1: per-graph precompute. grid=256 blocks (one per graph), 128 threads.
//  - z_proj[b] = relu(z[b] @ lp_w + lp_b)                [128]
//  - zc[b]     = z_proj[b] @ nd1_w                       [64]
//  - P1[b]     = z_proj[b] @ ed1_w[0:128]                [64]
//  - P2[b]     = z_proj[b] @ ed1_w[128:256]              [64]
//  - pred_energy[b], pred_stress[b]
// ---------------------------------------------------------------------------
__global__ void precompute_kernel(
    const float* __restrict__ z,
    const float* __restrict__ lp_w, const float* __restrict__ lp_b,
    const float* __restrict__ nd1_w,
    const float* __restrict__ ed1_w,
    const float* __restrict__ en1_w, const float* __restrict__ en1_b,
    const float* __restrict__ en2_w, const float* __restrict__ en2_b,
    const float* __restrict__ st1_w, const float* __restrict__ st1_b,
    const float* __restrict__ st2_w, const float* __restrict__ st2_b,
    float* __restrict__ z_proj, float* __restrict__ zc,
    float* __restrict__ P1, float* __restrict__ P2,
    float* __restrict__ out_energy, float* __restrict__ out_stress)
{
    const int b = blockIdx.x;
    const int t = threadIdx.x;  // 128 threads

    __shared__ float zrow[LATENT];
    __shared__ float zp[TWOH];
    __shared__ float h_en[HID];
    __shared__ float h_st[HID];

    if (t < LATENT) zrow[t] = z[b * LATENT + t];
    __syncthreads();

    // z_proj row (all 128 threads)
    {
        float a = lp_b[t];
        #pragma unroll
        for (int k = 0; k < LATENT; ++k)
            a = fmaf(zrow[k], lp_w[k * TWOH + t], a);
        a = fmaxf(a, 0.f);
        zp[t] = a;
        z_proj[b * TWOH + t] = a;
    }

    // energy / stress hidden layers (threads 0..63)
    if (t < HID) {
        float ae = en1_b[t];
        float as = st1_b[t];
        #pragma unroll
        for (int k = 0; k < LATENT; ++k) {
            ae = fmaf(zrow[k], en1_w[k * HID + t], ae);
            as = fmaf(zrow[k], st1_w[k * HID + t], as);
        }
        h_en[t] = fmaxf(ae, 0.f);
        h_st[t] = fmaxf(as, 0.f);
    }
    __syncthreads();

    // zc / P1 / P2 (threads 0..63): 128-dot each
    if (t < HID) {
        float a = 0.f, p1 = 0.f, p2 = 0.f;
        #pragma unroll 8
        for (int k = 0; k < TWOH; ++k) {
            const float zk = zp[k];
            a  = fmaf(zk, nd1_w[k * HID + t], a);
            p1 = fmaf(zk, ed1_w[k * HID + t], p1);
            p2 = fmaf(zk, ed1_w[(TWOH + k) * HID + t], p2);
        }
        zc[b * HID + t] = a;
        P1[b * HID + t] = p1;
        P2[b * HID + t] = p2;
    }

    // heads
    if (t < 2) {
        float a = en2_b[t];
        #pragma unroll 8
        for (int k = 0; k < HID; ++k) a = fmaf(h_en[k], en2_w[k * 2 + t], a);
        out_energy[b * 2 + t] = a;
    }
    if (t >= 16 && t < 25) {
        const int j = t - 16;
        float a = st2_b[j];
        #pragma unroll 8
        for (int k = 0; k < HID; ++k) a = fmaf(h_st[k], st2_w[k * 9 + j], a);
        out_stress[b * 9 + j] = a;
    }
}

// ---------------------------------------------------------------------------
// Kernel 2: edge pair table. grid=256 (gs), block=256 (gd).
// T4[gs][gd] = relu(P1[gs] + P2[gd] + ed1_b) @ ed2_w + ed2_b  (3 vals + pad)
// ---------------------------------------------------------------------------
__global__ void edge_table_kernel(
    const float* __restrict__ P1, const float* __restrict__ P2,
    const float* __restrict__ ed1_b,
    const float* __restrict__ ed2_w, const float* __restrict__ ed2_b,
    float4* __restrict__ T4)
{
    const int gs = blockIdx.x;
    const int t  = threadIdx.x;   // = gd

    __shared__ float p1s[HID];
    __shared__ float b1s[HID];
    __shared__ float w2s[HID * 3];
    __shared__ float b2s[3];

    if (t < HID) { p1s[t] = P1[gs * HID + t]; b1s[t] = ed1_b[t]; }
    if (t >= 64 && t < 64 + HID * 3) w2s[t - 64] = ed2_w[t - 64];
    if (t < 3) b2s[t] = ed2_b[t];
    __syncthreads();

    float o0 = b2s[0], o1 = b2s[1], o2 = b2s[2];
    const float* __restrict__ p2 = &P2[t * HID];
    #pragma unroll 8
    for (int k = 0; k < HID; ++k) {
        float h = fmaxf(p1s[k] + p2[k] + b1s[k], 0.f);
        o0 = fmaf(h, w2s[k * 3 + 0], o0);
        o1 = fmaf(h, w2s[k * 3 + 1], o1);
        o2 = fmaf(h, w2s[k * 3 + 2], o2);
    }
    T4[gs * NB + t] = make_float4(o0, o1, o2, 0.f);
}

// ---------------------------------------------------------------------------
// Kernel 3: node path (the FLOP floor).
//   nep = relu(emb @ nep_w + nep_b)            [128]
//   tt  = relu(nep @ nd1_w + nd1_b + zc[g])    [64]
//   out = tt @ nd2_w + nd2_b                   [4]
// 64 nodes / block, 256 threads, fused 2-stage register-tiled GEMM.
// LDS: embT[128][68] (transposed emb tile, reused as t_lds) + nepT[128][68].
// ---------------------------------------------------------------------------
#define MT 64
#define LDP 68   // padded leading dim (floats): breaks bank alignment, keeps 16B align

__global__ __launch_bounds__(256, 2)
void node_kernel(
    const float* __restrict__ node_emb,
    const int*   __restrict__ graph_id,
    const float* __restrict__ nep_w, const float* __restrict__ nep_b,
    const float* __restrict__ nd1_w, const float* __restrict__ nd1_b,
    const float* __restrict__ nd2_w, const float* __restrict__ nd2_b,
    const float* __restrict__ zc,
    float* __restrict__ out_node)
{
    __shared__ float embT[TWOH][LDP];   // [k][node] ; later reused as t_lds[64][LDP]
    __shared__ float nepT[TWOH][LDP];   // [c][node]
    __shared__ int   gid_s[MT];

    const int tid = threadIdx.x;
    const int n0  = blockIdx.x * MT;

    // ---- Phase 0: stage emb tile (transposed) + graph ids ----
    {
        const int nl = tid >> 2;        // node 0..63
        const int q  = tid & 3;
        const float4* __restrict__ emb4 =
            reinterpret_cast<const float4*>(node_emb) + (size_t)(n0 + nl) * 32;
        #pragma unroll
        for (int j = 0; j < 8; ++j) {
            const int k4 = j * 4 + q;           // float4 index within row
            const float4 v = emb4[k4];
            const int k = k4 * 4;
            embT[k + 0][nl] = v.x;
            embT[k + 1][nl] = v.y;
            embT[k + 2][nl] = v.z;
            embT[k + 3][nl] = v.w;
        }
        if (tid < MT) gid_s[tid] = graph_id[n0 + tid];
    }
    __syncthreads();

    const int ng = tid & 15;            // node group (4 nodes)
    const int cg = tid >> 4;            // channel group
    const int nb = ng * 4;

    // ---- Phase 1: nep = relu(emb @ nep_w + b): each thread 4 nodes x 8 ch ----
    {
        const int cb = cg * 8;
        float acc[4][8];
        #pragma unroll
        for (int i = 0; i < 4; ++i)
            #pragma unroll
            for (int j = 0; j < 8; ++j) acc[i][j] = 0.f;

        #pragma unroll 8
        for (int k = 0; k < TWOH; ++k) {
            const float4 e  = *reinterpret_cast<const float4*>(&embT[k][nb]);
            const float4 wa = *reinterpret_cast<const float4*>(&nep_w[k * TWOH + cb]);
            const float4 wb = *reinterpret_cast<const float4*>(&nep_w[k * TWOH + cb + 4]);
            const float ev[4] = {e.x, e.y, e.z, e.w};
            const float wv[8] = {wa.x, wa.y, wa.z, wa.w, wb.x, wb.y, wb.z, wb.w};
            #pragma unroll
            for (int i = 0; i < 4; ++i)
                #pragma unroll
                for (int j = 0; j < 8; ++j)
                    acc[i][j] = fmaf(ev[i], wv[j], acc[i][j]);
        }

        const float4 nb0 = *reinterpret_cast<const float4*>(&nep_b[cb]);
        const float4 nb1 = *reinterpret_cast<const float4*>(&nep_b[cb + 4]);
        const float bv[8] = {nb0.x, nb0.y, nb0.z, nb0.w, nb1.x, nb1.y, nb1.z, nb1.w};
        #pragma unroll
        for (int j = 0; j < 8; ++j) {
            const int c = cb + j;
            float4 v;
            v.x = fmaxf(acc[0][j] + bv[j], 0.f);
            v.y = fmaxf(acc[1][j] + bv[j], 0.f);
            v.z = fmaxf(acc[2][j] + bv[j], 0.f);
            v.w = fmaxf(acc[3][j] + bv[j], 0.f);
            *reinterpret_cast<float4*>(&nepT[c][nb]) = v;
        }
    }
    __syncthreads();

    // ---- Phase 2: tt = relu(nep @ nd1_w + nd1_b + zc[g]): 4 nodes x 4 ch ----
    float* __restrict__ tls = &embT[0][0];   // reuse embT as t_lds[64][LDP]
    {
        const int c2b = cg * 4;
        float a2[4][4];
        #pragma unroll
        for (int i = 0; i < 4; ++i)
            #pragma unroll
            for (int j = 0; j < 4; ++j) a2[i][j] = 0.f;

        #pragma unroll 8
        for (int k = 0; k < TWOH; ++k) {
            const float4 p = *reinterpret_cast<const float4*>(&nepT[k][nb]);
            const float4 w = *reinterpret_cast<const float4*>(&nd1_w[k * HID + c2b]);
            const float pv[4] = {p.x, p.y, p.z, p.w};
            const float wv[4] = {w.x, w.y, w.z, w.w};
            #pragma unroll
            for (int i = 0; i < 4; ++i)
                #pragma unroll
                for (int j = 0; j < 4; ++j)
                    a2[i][j] = fmaf(pv[i], wv[j], a2[i][j]);
        }

        const float4 b4 = *reinterpret_cast<const float4*>(&nd1_b[c2b]);
        #pragma unroll
        for (int i = 0; i < 4; ++i) {
            const int g = gid_s[nb + i];
            const float4 z4 = *reinterpret_cast<const float4*>(&zc[g * HID + c2b]);
            float4 v;
            v.x = fmaxf(a2[i][0] + b4.x + z4.x, 0.f);
            v.y = fmaxf(a2[i][1] + b4.y + z4.y, 0.f);
            v.z = fmaxf(a2[i][2] + b4.z + z4.z, 0.f);
            v.w = fmaxf(a2[i][3] + b4.w + z4.w, 0.f);
            *reinterpret_cast<float4*>(&tls[(nb + i) * LDP + c2b]) = v;
        }
    }
    __syncthreads();

    // ---- Phase 3: out = tt @ nd2_w + nd2_b: thread = (node, out_ch) ----
    {
        const int n = tid >> 2;
        const int o = tid & 3;
        float a = nd2_b[o];
        #pragma unroll 8
        for (int k = 0; k < HID; ++k)
            a = fmaf(tls[n * LDP + k], nd2_w[k * 4 + o], a);
        out_node[(size_t)(n0 + n) * 4 + o] = a;
    }
}

// ---------------------------------------------------------------------------
// Kernel 4: edge scatter — pure gather from the pair table.
// ---------------------------------------------------------------------------
__global__ void edge_kernel(
    const int* __restrict__ src, const int* __restrict__ dst,
    const int* __restrict__ graph_id,
    const float4* __restrict__ T4,
    float* __restrict__ out_edge)
{
    const int e = blockIdx.x * blockDim.x + threadIdx.x;
    if (e >= NE) return;
    const int s = src[e];
    const int d = dst[e];
    const int gs = graph_id[s];
    const int gd = graph_id[d];
    const float4 t = T4[gs * NB + gd];
    out_edge[(size_t)e * 3 + 0] = t.x;
    out_edge[(size_t)e * 3 + 1] = t.y;
    out_edge[(size_t)e * 3 + 2] = t.z;
}

// ---------------------------------------------------------------------------
extern "C" void kernel_launch(void* const* d_in, const int* in_sizes, int n_in,
                              void* d_out, int out_size, void* d_ws, size_t ws_size,
                              hipStream_t stream)
{
    const float* z        = (const float*)d_in[0];
    const float* node_emb = (const float*)d_in[1];
    const int*   graph_id = (const int*)  d_in[2];
    const int*   src      = (const int*)  d_in[3];
    const int*   dst      = (const int*)  d_in[4];
    const float* lp_w  = (const float*)d_in[5];
    const float* lp_b  = (const float*)d_in[6];
    const float* nep_w = (const float*)d_in[7];
    const float* nep_b = (const float*)d_in[8];
    const float* nd1_w = (const float*)d_in[9];
    const float* nd1_b = (const float*)d_in[10];
    const float* nd2_w = (const float*)d_in[11];
    const float* nd2_b = (const float*)d_in[12];
    const float* ed1_w = (const float*)d_in[13];
    const float* ed1_b = (const float*)d_in[14];
    const float* ed2_w = (const float*)d_in[15];
    const float* ed2_b = (const float*)d_in[16];
    const float* en1_w = (const float*)d_in[17];
    const float* en1_b = (const float*)d_in[18];
    const float* en2_w = (const float*)d_in[19];
    const float* en2_b = (const float*)d_in[20];
    const float* st1_w = (const float*)d_in[21];
    const float* st1_b = (const float*)d_in[22];
    const float* st2_w = (const float*)d_in[23];
    const float* st2_b = (const float*)d_in[24];

    float* out = (float*)d_out;
    float* out_node   = out + OUT_NODE_OFF;
    float* out_edge   = out + OUT_EDGE_OFF;
    float* out_energy = out + OUT_ENERGY_OFF;
    float* out_stress = out + OUT_STRESS_OFF;

    float* ws     = (float*)d_ws;
    float* z_proj = ws + WS_ZPROJ;
    float* zc     = ws + WS_ZC;
    float* P1     = ws + WS_P1;
    float* P2     = ws + WS_P2;
    float4* T4    = (float4*)(ws + WS_T4);

    precompute_kernel<<<NB, 128, 0, stream>>>(
        z, lp_w, lp_b, nd1_w, ed1_w,
        en1_w, en1_b, en2_w, en2_b, st1_w, st1_b, st2_w, st2_b,
        z_proj, zc, P1, P2, out_energy, out_stress);

    edge_table_kernel<<<NB, NB, 0, stream>>>(P1, P2, ed1_b, ed2_w, ed2_b, T4);

    node_kernel<<<NN / MT, 256, 0, stream>>>(
        node_emb, graph_id, nep_w, nep_b, nd1_w, nd1_b, nd2_w, nd2_b,
        zc, out_node);

    edge_kernel<<<(NE + 255) / 256, 256, 0, stream>>>(
        src, dst, graph_id, T4, out_edge);
}

// Round 2
// 310.558 us; speedup vs baseline: 1.2701x; 1.2701x over previous
//
#include <hip/hip_runtime.h>
#include <hip/hip_bf16.h>

// Problem constants (fixed by the reference)
#define LATENT 32
#define HID 64
#define NB 256          // batch (graphs)
#define NN 200000       // nodes
#define NE 1500000      // edges
#define TWOH 128        // 2*HID

// Output layout (flat floats in d_out)
#define OUT_NODE_OFF   0
#define OUT_EDGE_OFF   (NN * 4)                   // 800000
#define OUT_ENERGY_OFF (OUT_EDGE_OFF + NE * 3)    // 5300000
#define OUT_STRESS_OFF (OUT_ENERGY_OFF + NB * 2)  // 5300512

// Workspace layout (flat floats in d_ws)
#define WS_ZPROJ 0                      // [256][128]
#define WS_ZC    (WS_ZPROJ + NB*TWOH)   // [256][64]  z_proj @ nd1_w
#define WS_P1    (WS_ZC + NB*HID)       // [256][64]  z_proj @ ed1_w[0:128]
#define WS_P2    (WS_P1 + NB*HID)       // [256][64]  z_proj @ ed1_w[128:256]
#define WS_T4    (WS_P2 + NB*HID)       // [256][256][4] edge pair table (float4)
#define WS_W1T   (WS_T4 + NB*NB*4)      // fp16 [128n][128k] = 8192 floats
#define WS_W2T   (WS_W1T + 8192)        // fp16 [64n][128k]  = 4096 floats

typedef _Float16 half8 __attribute__((ext_vector_type(8)));
typedef _Float16 half4 __attribute__((ext_vector_type(4)));
typedef float f32x4 __attribute__((ext_vector_type(4)));

// ---------------------------------------------------------------------------
// Kernel 1: per-graph precompute (unchanged from R1 — not a hot kernel).
// ---------------------------------------------------------------------------
__global__ void precompute_kernel(
    const float* __restrict__ z,
    const float* __restrict__ lp_w, const float* __restrict__ lp_b,
    const float* __restrict__ nd1_w,
    const float* __restrict__ ed1_w,
    const float* __restrict__ en1_w, const float* __restrict__ en1_b,
    const float* __restrict__ en2_w, const float* __restrict__ en2_b,
    const float* __restrict__ st1_w, const float* __restrict__ st1_b,
    const float* __restrict__ st2_w, const float* __restrict__ st2_b,
    float* __restrict__ z_proj, float* __restrict__ zc,
    float* __restrict__ P1, float* __restrict__ P2,
    float* __restrict__ out_energy, float* __restrict__ out_stress)
{
    const int b = blockIdx.x;
    const int t = threadIdx.x;  // 128 threads

    __shared__ float zrow[LATENT];
    __shared__ float zp[TWOH];
    __shared__ float h_en[HID];
    __shared__ float h_st[HID];

    if (t < LATENT) zrow[t] = z[b * LATENT + t];
    __syncthreads();

    {
        float a = lp_b[t];
        #pragma unroll
        for (int k = 0; k < LATENT; ++k)
            a = fmaf(zrow[k], lp_w[k * TWOH + t], a);
        a = fmaxf(a, 0.f);
        zp[t] = a;
        z_proj[b * TWOH + t] = a;
    }

    if (t < HID) {
        float ae = en1_b[t];
        float as = st1_b[t];
        #pragma unroll
        for (int k = 0; k < LATENT; ++k) {
            ae = fmaf(zrow[k], en1_w[k * HID + t], ae);
            as = fmaf(zrow[k], st1_w[k * HID + t], as);
        }
        h_en[t] = fmaxf(ae, 0.f);
        h_st[t] = fmaxf(as, 0.f);
    }
    __syncthreads();

    if (t < HID) {
        float a = 0.f, p1 = 0.f, p2 = 0.f;
        #pragma unroll 8
        for (int k = 0; k < TWOH; ++k) {
            const float zk = zp[k];
            a  = fmaf(zk, nd1_w[k * HID + t], a);
            p1 = fmaf(zk, ed1_w[k * HID + t], p1);
            p2 = fmaf(zk, ed1_w[(TWOH + k) * HID + t], p2);
        }
        zc[b * HID + t] = a;
        P1[b * HID + t] = p1;
        P2[b * HID + t] = p2;
    }

    if (t < 2) {
        float a = en2_b[t];
        #pragma unroll 8
        for (int k = 0; k < HID; ++k) a = fmaf(h_en[k], en2_w[k * 2 + t], a);
        out_energy[b * 2 + t] = a;
    }
    if (t >= 16 && t < 25) {
        const int j = t - 16;
        float a = st2_b[j];
        #pragma unroll 8
        for (int k = 0; k < HID; ++k) a = fmaf(h_st[k], st2_w[k * 9 + j], a);
        out_stress[b * 9 + j] = a;
    }
}

// ---------------------------------------------------------------------------
// Kernel 1b: fp16 weight transpose for the MFMA node path.
//   w1T[n*128+k] = (fp16) nep_w[k*128+n]   (128x128)
//   w2T[n*128+k] = (fp16) nd1_w[k*64+n]    (64x128)
// ---------------------------------------------------------------------------
__global__ void prep_weights_kernel(
    const float* __restrict__ nep_w, const float* __restrict__ nd1_w,
    _Float16* __restrict__ w1T, _Float16* __restrict__ w2T)
{
    const int i = blockIdx.x * 256 + threadIdx.x;
    if (i < TWOH * TWOH) {
        const int n = i >> 7, k = i & 127;
        w1T[i] = (_Float16)nep_w[k * TWOH + n];
    }
    if (i < HID * TWOH) {
        const int n = i >> 7, k = i & 127;
        w2T[i] = (_Float16)nd1_w[k * HID + n];
    }
}

// ---------------------------------------------------------------------------
// Kernel 2: edge pair table (unchanged).
// ---------------------------------------------------------------------------
__global__ void edge_table_kernel(
    const float* __restrict__ P1, const float* __restrict__ P2,
    const float* __restrict__ ed1_b,
    const float* __restrict__ ed2_w, const float* __restrict__ ed2_b,
    float4* __restrict__ T4)
{
    const int gs = blockIdx.x;
    const int t  = threadIdx.x;   // = gd

    __shared__ float p1s[HID];
    __shared__ float b1s[HID];
    __shared__ float w2s[HID * 3];
    __shared__ float b2s[3];

    if (t < HID) { p1s[t] = P1[gs * HID + t]; b1s[t] = ed1_b[t]; }
    if (t >= 64 && t < 64 + HID * 3) w2s[t - 64] = ed2_w[t - 64];
    if (t < 3) b2s[t] = ed2_b[t];
    __syncthreads();

    float o0 = b2s[0], o1 = b2s[1], o2 = b2s[2];
    const float* __restrict__ p2 = &P2[t * HID];
    #pragma unroll 8
    for (int k = 0; k < HID; ++k) {
        float h = fmaxf(p1s[k] + p2[k] + b1s[k], 0.f);
        o0 = fmaf(h, w2s[k * 3 + 0], o0);
        o1 = fmaf(h, w2s[k * 3 + 1], o1);
        o2 = fmaf(h, w2s[k * 3 + 2], o2);
    }
    T4[gs * NB + t] = make_float4(o0, o1, o2, 0.f);
}

// ---------------------------------------------------------------------------
// Kernel 3: node path via fp16 MFMA (fp32 accumulate).
//   stage1: nep = relu(emb @ nep_w + b)   M=64/block, N=128, K=128
//   stage2: tt  = relu(nep @ nd1_w + b + zc[g])  N=64, K=128
//   stage3: out = tt @ nd2_w + b  (VALU, K=64 -> 4)
// 256 threads = 4 waves; wave w owns rows 16w..16w+15.
// LDS: embT/nep fp16 [64][128] XOR-swizzled (T2: 16 rows @ same k would be a
// 16-way conflict unswizzled); tt fp32 [64][69] (69%32=5 -> <=2-way on r/w).
// ~51 KB LDS -> 3 blocks/CU.
// MFMA frag layouts (gfx950 16x16x32, verified pattern from learn_hip m89/m92):
//   A: row=lane&15, k=(lane>>4)*8+j (8 contiguous)   B: col=lane&15, same k
//   C/D: col(N)=lane&15, row(M)=(lane>>4)*4+reg
// ---------------------------------------------------------------------------
#define MT 64
#define SWZ(r) (((r) & 15) << 3)   // element-index XOR (16B granularity)

__global__ __launch_bounds__(256, 2)
void node_kernel(
    const float* __restrict__ node_emb,
    const int*   __restrict__ graph_id,
    const _Float16* __restrict__ w1T,
    const float* __restrict__ nep_b,
    const _Float16* __restrict__ w2T,
    const float* __restrict__ nd1_b,
    const float* __restrict__ nd2_w, const float* __restrict__ nd2_b,
    const float* __restrict__ zc,
    float* __restrict__ out_node)
{
    __shared__ _Float16 embT[MT * TWOH];   // 16 KB, swizzled [row][k]
    __shared__ _Float16 nep [MT * TWOH];   // 16 KB, swizzled [row][n->k]
    __shared__ float    tt  [MT * 69];     // 17.25 KB
    __shared__ float    w3  [HID * 4];     // 1 KB
    __shared__ int      gid_s[MT];

    const int tid = threadIdx.x;
    const int n0  = blockIdx.x * MT;

    // ---- Phase 0: stage emb tile -> fp16 LDS (swizzled); gid; w3 ----
    {
        const int c4 = tid & 31;            // float4 col 0..31
        #pragma unroll
        for (int pass = 0; pass < 8; ++pass) {
            const int row = (tid >> 5) + pass * 8;
            const float4 v = *reinterpret_cast<const float4*>(
                node_emb + (size_t)(n0 + row) * TWOH + c4 * 4);
            half4 h;
            h[0] = (_Float16)v.x; h[1] = (_Float16)v.y;
            h[2] = (_Float16)v.z; h[3] = (_Float16)v.w;
            const int e = row * TWOH + c4 * 4;
            *reinterpret_cast<half4*>(&embT[e ^ SWZ(row)]) = h;
        }
        if (tid < MT) gid_s[tid] = graph_id[n0 + tid];
        w3[tid] = nd2_w[tid];               // 256 = 64*4 exactly
    }
    __syncthreads();

    const int wv   = tid >> 6;
    const int lane = tid & 63;
    const int lrow = lane & 15;
    const int kg   = lane >> 4;

    // ---- Stage 1: nep = relu(emb @ W1 + b1) ----
    {
        half8 a[4];
        #pragma unroll
        for (int kb = 0; kb < 4; ++kb) {
            const int r = wv * 16 + lrow;
            const int e = r * TWOH + kb * 32 + kg * 8;
            a[kb] = *reinterpret_cast<const half8*>(&embT[e ^ SWZ(r)]);
        }
        f32x4 acc[8];
        #pragma unroll
        for (int tn = 0; tn < 8; ++tn) acc[tn] = (f32x4){0.f, 0.f, 0.f, 0.f};

        #pragma unroll
        for (int tn = 0; tn < 8; ++tn) {
            const int n = tn * 16 + lrow;
            #pragma unroll
            for (int kb = 0; kb < 4; ++kb) {
                const half8 b = *reinterpret_cast<const half8*>(
                    &w1T[n * TWOH + kb * 32 + kg * 8]);
                acc[tn] = __builtin_amdgcn_mfma_f32_16x16x32_f16(a[kb], b, acc[tn], 0, 0, 0);
            }
        }
        // epilogue: +bias, relu, fp16, swizzled LDS store
        #pragma unroll
        for (int tn = 0; tn < 8; ++tn) {
            const int n = tn * 16 + lrow;
            const float bn = nep_b[n];
            #pragma unroll
            for (int reg = 0; reg < 4; ++reg) {
                const int r = wv * 16 + kg * 4 + reg;
                const float v = fmaxf(acc[tn][reg] + bn, 0.f);
                nep[(r * TWOH + n) ^ SWZ(r)] = (_Float16)v;
            }
        }
    }
    __syncthreads();

    // ---- Stage 2: tt = relu(nep @ W2 + b2 + zc[g]) ----
    {
        half8 a2[4];
        #pragma unroll
        for (int kb = 0; kb < 4; ++kb) {
            const int r = wv * 16 + lrow;
            const int e = r * TWOH + kb * 32 + kg * 8;
            a2[kb] = *reinterpret_cast<const half8*>(&nep[e ^ SWZ(r)]);
        }
        f32x4 acc2[4];
        #pragma unroll
        for (int tn = 0; tn < 4; ++tn) acc2[tn] = (f32x4){0.f, 0.f, 0.f, 0.f};

        #pragma unroll
        for (int tn = 0; tn < 4; ++tn) {
            const int n = tn * 16 + lrow;
            #pragma unroll
            for (int kb = 0; kb < 4; ++kb) {
                const half8 b = *reinterpret_cast<const half8*>(
                    &w2T[n * TWOH + kb * 32 + kg * 8]);
                acc2[tn] = __builtin_amdgcn_mfma_f32_16x16x32_f16(a2[kb], b, acc2[tn], 0, 0, 0);
            }
        }
        #pragma unroll
        for (int tn = 0; tn < 4; ++tn) {
            const int n = tn * 16 + lrow;
            const float b1 = nd1_b[n];
            #pragma unroll
            for (int reg = 0; reg < 4; ++reg) {
                const int r = wv * 16 + kg * 4 + reg;
                const int g = gid_s[r];
                const float v = fmaxf(acc2[tn][reg] + b1 + zc[g * HID + n], 0.f);
                tt[r * 69 + n] = v;
            }
        }
    }
    __syncthreads();

    // ---- Stage 3: out = tt @ W3 + b3 (VALU) ----
    {
        const int nd = tid >> 2;
        const int o  = tid & 3;
        float a = nd2_b[o];
        #pragma unroll 8
        for (int k = 0; k < HID; ++k)
            a = fmaf(tt[nd * 69 + k], w3[k * 4 + o], a);
        out_node[(size_t)(n0 + nd) * 4 + o] = a;
    }
}

// ---------------------------------------------------------------------------
// Kernel 4: edge scatter — 4 edges/thread, float4 stores.
// ---------------------------------------------------------------------------
__global__ void edge_kernel(
    const int* __restrict__ src, const int* __restrict__ dst,
    const int* __restrict__ graph_id,
    const float4* __restrict__ T4,
    float* __restrict__ out_edge)
{
    const int e0 = (blockIdx.x * 256 + threadIdx.x) * 4;
    if (e0 >= NE) return;
    const int4 s4 = *reinterpret_cast<const int4*>(&src[e0]);
    const int4 d4 = *reinterpret_cast<const int4*>(&dst[e0]);
    const int ss[4] = {s4.x, s4.y, s4.z, s4.w};
    const int dd[4] = {d4.x, d4.y, d4.z, d4.w};
    float o[12];
    #pragma unroll
    for (int j = 0; j < 4; ++j) {
        const int gs = graph_id[ss[j]];
        const int gd = graph_id[dd[j]];
        const float4 t = T4[gs * NB + gd];
        o[j * 3 + 0] = t.x; o[j * 3 + 1] = t.y; o[j * 3 + 2] = t.z;
    }
    float4* outp = reinterpret_cast<float4*>(&out_edge[(size_t)e0 * 3]);
    outp[0] = make_float4(o[0], o[1], o[2],  o[3]);
    outp[1] = make_float4(o[4], o[5], o[6],  o[7]);
    outp[2] = make_float4(o[8], o[9], o[10], o[11]);
}

// ---------------------------------------------------------------------------
extern "C" void kernel_launch(void* const* d_in, const int* in_sizes, int n_in,
                              void* d_out, int out_size, void* d_ws, size_t ws_size,
                              hipStream_t stream)
{
    const float* z        = (const float*)d_in[0];
    const float* node_emb = (const float*)d_in[1];
    const int*   graph_id = (const int*)  d_in[2];
    const int*   src      = (const int*)  d_in[3];
    const int*   dst      = (const int*)  d_in[4];
    const float* lp_w  = (const float*)d_in[5];
    const float* lp_b  = (const float*)d_in[6];
    const float* nep_w = (const float*)d_in[7];
    const float* nep_b = (const float*)d_in[8];
    const float* nd1_w = (const float*)d_in[9];
    const float* nd1_b = (const float*)d_in[10];
    const float* nd2_w = (const float*)d_in[11];
    const float* nd2_b = (const float*)d_in[12];
    const float* ed1_w = (const float*)d_in[13];
    const float* ed1_b = (const float*)d_in[14];
    const float* ed2_w = (const float*)d_in[15];
    const float* ed2_b = (const float*)d_in[16];
    const float* en1_w = (const float*)d_in[17];
    const float* en1_b = (const float*)d_in[18];
    const float* en2_w = (const float*)d_in[19];
    const float* en2_b = (const float*)d_in[20];
    const float* st1_w = (const float*)d_in[21];
    const float* st1_b = (const float*)d_in[22];
    const float* st2_w = (const float*)d_in[23];
    const float* st2_b = (const float*)d_in[24];

    float* out = (float*)d_out;
    float* out_node   = out + OUT_NODE_OFF;
    float* out_edge   = out + OUT_EDGE_OFF;
    float* out_energy = out + OUT_ENERGY_OFF;
    float* out_stress = out + OUT_STRESS_OFF;

    float* ws     = (float*)d_ws;
    float* z_proj = ws + WS_ZPROJ;
    float* zc     = ws + WS_ZC;
    float* P1     = ws + WS_P1;
    float* P2     = ws + WS_P2;
    float4* T4    = (float4*)(ws + WS_T4);
    _Float16* w1T = (_Float16*)(ws + WS_W1T);
    _Float16* w2T = (_Float16*)(ws + WS_W2T);

    precompute_kernel<<<NB, 128, 0, stream>>>(
        z, lp_w, lp_b, nd1_w, ed1_w,
        en1_w, en1_b, en2_w, en2_b, st1_w, st1_b, st2_w, st2_b,
        z_proj, zc, P1, P2, out_energy, out_stress);

    prep_weights_kernel<<<64, 256, 0, stream>>>(nep_w, nd1_w, w1T, w2T);

    edge_table_kernel<<<NB, NB, 0, stream>>>(P1, P2, ed1_b, ed2_w, ed2_b, T4);

    node_kernel<<<NN / MT, 256, 0, stream>>>(
        node_emb, graph_id, w1T, nep_b, w2T, nd1_b, nd2_w, nd2_b,
        zc, out_node);

    edge_kernel<<<(NE / 4 + 255) / 256, 256, 0, stream>>>(
        src, dst, graph_id, T4, out_edge);
}

// Round 3
// 249.484 us; speedup vs baseline: 1.5810x; 1.2448x over previous
//
#include <hip/hip_runtime.h>
#include <hip/hip_bf16.h>

// Problem constants (fixed by the reference)
#define LATENT 32
#define HID 64
#define NB 256          // batch (graphs)
#define NN 200000       // nodes
#define NE 1500000      // edges
#define TWOH 128        // 2*HID

// Output layout (flat floats in d_out)
#define OUT_NODE_OFF   0
#define OUT_EDGE_OFF   (NN * 4)                   // 800000
#define OUT_ENERGY_OFF (OUT_EDGE_OFF + NE * 3)    // 5300000
#define OUT_STRESS_OFF (OUT_ENERGY_OFF + NB * 2)  // 5300512

// Workspace layout (flat floats in d_ws)
#define WS_ZPROJ 0
#define WS_ZC    (WS_ZPROJ + NB*TWOH)
#define WS_P1    (WS_ZC + NB*HID)
#define WS_P2    (WS_P1 + NB*HID)
#define WS_T4    (WS_P2 + NB*HID)
#define WS_W1T   (WS_T4 + NB*NB*4)      // fp16 [128ch][128k]
#define WS_W2T   (WS_W1T + 8192)        // fp16 [64ch][128k]

typedef _Float16 half8 __attribute__((ext_vector_type(8)));
typedef _Float16 half4 __attribute__((ext_vector_type(4)));
typedef float f32x4 __attribute__((ext_vector_type(4)));

#define MT 64                 // nodes per tile
#define NTILES (NN / MT)      // 3125
#define NODE_BLOCKS 512       // 2 persistent blocks/CU
#define EDGE_BLOCKS ((NE / 4 + 255) / 256)  // 1465
#define SWZ(r) (((r) & 15) << 3)  // element-index XOR swizzle (16B gran)

// ---------------------------------------------------------------------------
// Kernel 1: per-graph precompute (blocks 0..255) + fp16 weight transpose
// (blocks 256..319). 256 threads.
// ---------------------------------------------------------------------------
__global__ void precompute_kernel(
    const float* __restrict__ z,
    const float* __restrict__ lp_w, const float* __restrict__ lp_b,
    const float* __restrict__ nd1_w,
    const float* __restrict__ ed1_w,
    const float* __restrict__ en1_w, const float* __restrict__ en1_b,
    const float* __restrict__ en2_w, const float* __restrict__ en2_b,
    const float* __restrict__ st1_w, const float* __restrict__ st1_b,
    const float* __restrict__ st2_w, const float* __restrict__ st2_b,
    const float* __restrict__ nep_w,
    float* __restrict__ z_proj, float* __restrict__ zc,
    float* __restrict__ P1, float* __restrict__ P2,
    _Float16* __restrict__ w1T, _Float16* __restrict__ w2T,
    float* __restrict__ out_energy, float* __restrict__ out_stress)
{
    const int t = threadIdx.x;

    if (blockIdx.x >= NB) {
        // weight transpose part
        const int i = (blockIdx.x - NB) * 256 + t;
        if (i < TWOH * TWOH) {
            const int n = i >> 7, k = i & 127;
            w1T[i] = (_Float16)nep_w[k * TWOH + n];
        }
        if (i < HID * TWOH) {
            const int n = i >> 7, k = i & 127;
            w2T[i] = (_Float16)nd1_w[k * HID + n];
        }
        return;
    }

    const int b = blockIdx.x;
    __shared__ float zrow[LATENT];
    __shared__ float zp[TWOH];
    __shared__ float h_en[HID];
    __shared__ float h_st[HID];

    if (t < LATENT) zrow[t] = z[b * LATENT + t];
    __syncthreads();

    if (t < TWOH) {
        float a = lp_b[t];
        #pragma unroll
        for (int k = 0; k < LATENT; ++k)
            a = fmaf(zrow[k], lp_w[k * TWOH + t], a);
        a = fmaxf(a, 0.f);
        zp[t] = a;
        z_proj[b * TWOH + t] = a;
    }
    if (t < HID) {
        float ae = en1_b[t];
        float as = st1_b[t];
        #pragma unroll
        for (int k = 0; k < LATENT; ++k) {
            ae = fmaf(zrow[k], en1_w[k * HID + t], ae);
            as = fmaf(zrow[k], st1_w[k * HID + t], as);
        }
        h_en[t] = fmaxf(ae, 0.f);
        h_st[t] = fmaxf(as, 0.f);
    }
    __syncthreads();

    if (t < HID) {
        float a = 0.f, p1 = 0.f, p2 = 0.f;
        #pragma unroll 8
        for (int k = 0; k < TWOH; ++k) {
            const float zk = zp[k];
            a  = fmaf(zk, nd1_w[k * HID + t], a);
            p1 = fmaf(zk, ed1_w[k * HID + t], p1);
            p2 = fmaf(zk, ed1_w[(TWOH + k) * HID + t], p2);
        }
        zc[b * HID + t] = a;
        P1[b * HID + t] = p1;
        P2[b * HID + t] = p2;
    }
    if (t < 2) {
        float a = en2_b[t];
        #pragma unroll 8
        for (int k = 0; k < HID; ++k) a = fmaf(h_en[k], en2_w[k * 2 + t], a);
        out_energy[b * 2 + t] = a;
    }
    if (t >= 16 && t < 25) {
        const int j = t - 16;
        float a = st2_b[j];
        #pragma unroll 8
        for (int k = 0; k < HID; ++k) a = fmaf(h_st[k], st2_w[k * 9 + j], a);
        out_stress[b * 9 + j] = a;
    }
}

// ---------------------------------------------------------------------------
// Kernel 2: edge pair table. grid=256 (gs), block=256 (gd).
// ---------------------------------------------------------------------------
__global__ void edge_table_kernel(
    const float* __restrict__ P1, const float* __restrict__ P2,
    const float* __restrict__ ed1_b,
    const float* __restrict__ ed2_w, const float* __restrict__ ed2_b,
    float4* __restrict__ T4)
{
    const int gs = blockIdx.x;
    const int t  = threadIdx.x;

    __shared__ float p1s[HID];
    __shared__ float b1s[HID];
    __shared__ float w2s[HID * 3];
    __shared__ float b2s[3];

    if (t < HID) { p1s[t] = P1[gs * HID + t]; b1s[t] = ed1_b[t]; }
    if (t >= 64 && t < 64 + HID * 3) w2s[t - 64] = ed2_w[t - 64];
    if (t < 3) b2s[t] = ed2_b[t];
    __syncthreads();

    float o0 = b2s[0], o1 = b2s[1], o2 = b2s[2];
    const float* __restrict__ p2 = &P2[t * HID];
    #pragma unroll 8
    for (int k = 0; k < HID; ++k) {
        float h = fmaxf(p1s[k] + p2[k] + b1s[k], 0.f);
        o0 = fmaf(h, w2s[k * 3 + 0], o0);
        o1 = fmaf(h, w2s[k * 3 + 1], o1);
        o2 = fmaf(h, w2s[k * 3 + 2], o2);
    }
    T4[gs * NB + t] = make_float4(o0, o1, o2, 0.f);
}

// ---------------------------------------------------------------------------
// Kernel 3: fused node path + edge scatter.
//  Blocks [0, NODE_BLOCKS): persistent, double-buffered node tiles.
//    Swapped-operand MFMA: nep^T = W1^T @ emb^T, tt^T = W2^T @ nep^T.
//    Weight A-fragments hoisted to registers (persistent blocks!); stage-3
//    in-register via shfl_xor; T14 async staging (load early, ds_write late).
//  Blocks [NODE_BLOCKS, +EDGE_BLOCKS): edge gather from pair table.
// ---------------------------------------------------------------------------
__global__ __launch_bounds__(256, 2)
void node_edge_kernel(
    const float* __restrict__ node_emb,
    const int*   __restrict__ graph_id,
    const _Float16* __restrict__ w1T,
    const float* __restrict__ nep_b,
    const _Float16* __restrict__ w2T,
    const float* __restrict__ nd1_b,
    const float* __restrict__ nd2_w, const float* __restrict__ nd2_b,
    const float* __restrict__ zc,
    const int* __restrict__ src, const int* __restrict__ dst,
    const float4* __restrict__ T4,
    float* __restrict__ out_node, float* __restrict__ out_edge)
{
    const int tid = threadIdx.x;
    const int bid = blockIdx.x;

    if (bid >= NODE_BLOCKS) {
        // ---------------- edge path ----------------
        const int e0 = ((bid - NODE_BLOCKS) * 256 + tid) * 4;
        if (e0 >= NE) return;
        const int4 s4 = *reinterpret_cast<const int4*>(&src[e0]);
        const int4 d4 = *reinterpret_cast<const int4*>(&dst[e0]);
        const int ss[4] = {s4.x, s4.y, s4.z, s4.w};
        const int dd[4] = {d4.x, d4.y, d4.z, d4.w};
        float o[12];
        #pragma unroll
        for (int j = 0; j < 4; ++j) {
            const int gs = graph_id[ss[j]];
            const int gd = graph_id[dd[j]];
            const float4 tv = T4[gs * NB + gd];
            o[j * 3 + 0] = tv.x; o[j * 3 + 1] = tv.y; o[j * 3 + 2] = tv.z;
        }
        float4* outp = reinterpret_cast<float4*>(&out_edge[(size_t)e0 * 3]);
        outp[0] = make_float4(o[0], o[1], o[2],  o[3]);
        outp[1] = make_float4(o[4], o[5], o[6],  o[7]);
        outp[2] = make_float4(o[8], o[9], o[10], o[11]);
        return;
    }

    // ---------------- node path (persistent) ----------------
    __shared__ _Float16 embL[2][MT * TWOH];   // 2 x 16 KB, swizzled [node][k]
    __shared__ _Float16 nepL[MT * TWOH];      // 16 KB, swizzled [node][ch]
    __shared__ float    partL[4 * MT * 4];    // 4 KB: [wave][node][o]
    __shared__ int      gidL[2][MT];

    const int wv   = tid >> 6;
    const int lane = tid & 63;
    const int lrow = lane & 15;
    const int kg   = lane >> 4;

    // ---- hoisted weights / biases (loaded once; persistent block) ----
    half8 w1A[2][4];   // stage1 A-frags: channels wv*32+cht*16+lrow, k=kb*32+kg*8
    half8 w2A[4];      // stage2 A-frags: channels wv*16+lrow
    #pragma unroll
    for (int cht = 0; cht < 2; ++cht)
        #pragma unroll
        for (int kb = 0; kb < 4; ++kb)
            w1A[cht][kb] = *reinterpret_cast<const half8*>(
                &w1T[(wv * 32 + cht * 16 + lrow) * TWOH + kb * 32 + kg * 8]);
    #pragma unroll
    for (int kb = 0; kb < 4; ++kb)
        w2A[kb] = *reinterpret_cast<const half8*>(
            &w2T[(wv * 16 + lrow) * TWOH + kb * 32 + kg * 8]);

    f32x4 b1r[2], b2r, w3r[4];
    #pragma unroll
    for (int cht = 0; cht < 2; ++cht)
        b1r[cht] = *reinterpret_cast<const f32x4*>(&nep_b[wv * 32 + cht * 16 + kg * 4]);
    b2r = *reinterpret_cast<const f32x4*>(&nd1_b[wv * 16 + kg * 4]);
    #pragma unroll
    for (int j = 0; j < 4; ++j)
        w3r[j] = *reinterpret_cast<const f32x4*>(&nd2_w[(wv * 16 + kg * 4 + j) * 4]);
    const float b3 = nd2_b[tid & 3];

    const int r0 = tid >> 2;      // staging: row within tile
    const int q0 = tid & 3;       // staging: quad phase

    // ---- prologue: stage tile(bid) into buffer 0 ----
    {
        const float4* s4 = reinterpret_cast<const float4*>(
            node_emb + (size_t)(bid * MT + r0) * TWOH);
        float4 rr[8];
        #pragma unroll
        for (int p = 0; p < 8; ++p) rr[p] = s4[q0 + 4 * p];
        #pragma unroll
        for (int p = 0; p < 8; ++p) {
            half4 h;
            h[0] = (_Float16)rr[p].x; h[1] = (_Float16)rr[p].y;
            h[2] = (_Float16)rr[p].z; h[3] = (_Float16)rr[p].w;
            const int e = r0 * TWOH + (q0 + 4 * p) * 4;
            *reinterpret_cast<half4*>(&embL[0][e ^ SWZ(r0)]) = h;
        }
        if (tid < MT) gidL[0][tid] = graph_id[bid * MT + tid];
    }
    __syncthreads();

    int cur = 0;
    for (int t = bid; t < NTILES; t += NODE_BLOCKS) {
        const int tn = t + NODE_BLOCKS;
        const bool have_next = (tn < NTILES);

        // ---- A: issue next tile's global loads (consumed in E) ----
        float4 rr[8];
        int gnext = 0;
        if (have_next) {
            const float4* s4 = reinterpret_cast<const float4*>(
                node_emb + (size_t)(tn * MT + r0) * TWOH);
            #pragma unroll
            for (int p = 0; p < 8; ++p) rr[p] = s4[q0 + 4 * p];
            if (tid < MT) gnext = graph_id[tn * MT + tid];
        }

        const _Float16* eb = embL[cur];

        // ---- B: stage1'  nep^T = relu(W1^T @ emb^T + b) ----
        f32x4 acc1[2][4];
        #pragma unroll
        for (int cht = 0; cht < 2; ++cht)
            #pragma unroll
            for (int nt = 0; nt < 4; ++nt)
                acc1[cht][nt] = (f32x4){0.f, 0.f, 0.f, 0.f};

        #pragma unroll
        for (int nt = 0; nt < 4; ++nt) {
            half8 eB[4];
            #pragma unroll
            for (int kb = 0; kb < 4; ++kb) {
                const int row = nt * 16 + lrow;
                const int e = row * TWOH + kb * 32 + kg * 8;
                eB[kb] = *reinterpret_cast<const half8*>(&eb[e ^ SWZ(row)]);
            }
            #pragma unroll
            for (int cht = 0; cht < 2; ++cht)
                #pragma unroll
                for (int kb = 0; kb < 4; ++kb)
                    acc1[cht][nt] = __builtin_amdgcn_mfma_f32_16x16x32_f16(
                        w1A[cht][kb], eB[kb], acc1[cht][nt], 0, 0, 0);
        }
        // epilogue: bias+relu -> fp16 -> packed b64 writes (col-contig channels)
        #pragma unroll
        for (int cht = 0; cht < 2; ++cht)
            #pragma unroll
            for (int nt = 0; nt < 4; ++nt) {
                const int node = nt * 16 + lrow;
                const int ch = wv * 32 + cht * 16 + kg * 4;
                half4 h;
                #pragma unroll
                for (int j = 0; j < 4; ++j)
                    h[j] = (_Float16)fmaxf(acc1[cht][nt][j] + b1r[cht][j], 0.f);
                *reinterpret_cast<half4*>(
                    &nepL[(node * TWOH + ch) ^ SWZ(node)]) = h;
            }
        __syncthreads();   // B1: nep ready

        // ---- C: stage2'  tt^T = relu(W2^T @ nep^T + b + zc[g])  + stage3 partials ----
        f32x4 acc2[4];
        #pragma unroll
        for (int nt = 0; nt < 4; ++nt) acc2[nt] = (f32x4){0.f, 0.f, 0.f, 0.f};

        #pragma unroll
        for (int nt = 0; nt < 4; ++nt) {
            half8 nB[4];
            #pragma unroll
            for (int kb = 0; kb < 4; ++kb) {
                const int row = nt * 16 + lrow;
                const int e = row * TWOH + kb * 32 + kg * 8;
                nB[kb] = *reinterpret_cast<const half8*>(&nepL[e ^ SWZ(row)]);
            }
            #pragma unroll
            for (int kb = 0; kb < 4; ++kb)
                acc2[nt] = __builtin_amdgcn_mfma_f32_16x16x32_f16(
                    w2A[kb], nB[kb], acc2[nt], 0, 0, 0);
        }

        f32x4 p[4];
        #pragma unroll
        for (int nt = 0; nt < 4; ++nt) {
            const int node = nt * 16 + lrow;
            const int g = gidL[cur][node];
            const f32x4 z4 = *reinterpret_cast<const f32x4*>(
                &zc[(size_t)g * HID + wv * 16 + kg * 4]);
            f32x4 t4;
            #pragma unroll
            for (int j = 0; j < 4; ++j)
                t4[j] = fmaxf(acc2[nt][j] + b2r[j] + z4[j], 0.f);
            f32x4 pp = t4[0] * w3r[0];
            pp += t4[1] * w3r[1];
            pp += t4[2] * w3r[2];
            pp += t4[3] * w3r[3];
            p[nt] = pp;
        }
        // reduce over channel groups (kg): lanes ^16, ^32
        #pragma unroll
        for (int nt = 0; nt < 4; ++nt) {
            #pragma unroll
            for (int j = 0; j < 4; ++j) {
                p[nt][j] += __shfl_xor(p[nt][j], 16, 64);
                p[nt][j] += __shfl_xor(p[nt][j], 32, 64);
            }
        }
        if (lane < 16) {
            #pragma unroll
            for (int nt = 0; nt < 4; ++nt)
                *reinterpret_cast<f32x4*>(
                    &partL[(wv * MT + nt * 16 + lrow) * 4]) = p[nt];
        }
        __syncthreads();   // B2: partials ready

        // ---- D: final cross-wave sum + store ----
        {
            const int node = r0;   // tid>>2
            const int o    = q0;   // tid&3
            const int ix = node * 4 + o;
            const float s = partL[ix] + partL[256 + ix] +
                            partL[512 + ix] + partL[768 + ix] + b3;
            out_node[(size_t)(t * MT + node) * 4 + o] = s;
        }

        // ---- E: write prefetched tile into other buffer ----
        if (have_next) {
            #pragma unroll
            for (int p8 = 0; p8 < 8; ++p8) {
                half4 h;
                h[0] = (_Float16)rr[p8].x; h[1] = (_Float16)rr[p8].y;
                h[2] = (_Float16)rr[p8].z; h[3] = (_Float16)rr[p8].w;
                const int e = r0 * TWOH + (q0 + 4 * p8) * 4;
                *reinterpret_cast<half4*>(&embL[cur ^ 1][e ^ SWZ(r0)]) = h;
            }
            if (tid < MT) gidL[cur ^ 1][tid] = gnext;
        }
        __syncthreads();   // B3: next buffer ready; partL consumed
        cur ^= 1;
    }
}

// ---------------------------------------------------------------------------
extern "C" void kernel_launch(void* const* d_in, const int* in_sizes, int n_in,
                              void* d_out, int out_size, void* d_ws, size_t ws_size,
                              hipStream_t stream)
{
    const float* z        = (const float*)d_in[0];
    const float* node_emb = (const float*)d_in[1];
    const int*   graph_id = (const int*)  d_in[2];
    const int*   src      = (const int*)  d_in[3];
    const int*   dst      = (const int*)  d_in[4];
    const float* lp_w  = (const float*)d_in[5];
    const float* lp_b  = (const float*)d_in[6];
    const float* nep_w = (const float*)d_in[7];
    const float* nep_b = (const float*)d_in[8];
    const float* nd1_w = (const float*)d_in[9];
    const float* nd1_b = (const float*)d_in[10];
    const float* nd2_w = (const float*)d_in[11];
    const float* nd2_b = (const float*)d_in[12];
    const float* ed1_w = (const float*)d_in[13];
    const float* ed1_b = (const float*)d_in[14];
    const float* ed2_w = (const float*)d_in[15];
    const float* ed2_b = (const float*)d_in[16];
    const float* en1_w = (const float*)d_in[17];
    const float* en1_b = (const float*)d_in[18];
    const float* en2_w = (const float*)d_in[19];
    const float* en2_b = (const float*)d_in[20];
    const float* st1_w = (const float*)d_in[21];
    const float* st1_b = (const float*)d_in[22];
    const float* st2_w = (const float*)d_in[23];
    const float* st2_b = (const float*)d_in[24];

    float* out = (float*)d_out;
    float* out_node   = out + OUT_NODE_OFF;
    float* out_edge   = out + OUT_EDGE_OFF;
    float* out_energy = out + OUT_ENERGY_OFF;
    float* out_stress = out + OUT_STRESS_OFF;

    float* ws     = (float*)d_ws;
    float* z_proj = ws + WS_ZPROJ;
    float* zc     = ws + WS_ZC;
    float* P1     = ws + WS_P1;
    float* P2     = ws + WS_P2;
    float4* T4    = (float4*)(ws + WS_T4);
    _Float16* w1T = (_Float16*)(ws + WS_W1T);
    _Float16* w2T = (_Float16*)(ws + WS_W2T);

    precompute_kernel<<<NB + 64, 256, 0, stream>>>(
        z, lp_w, lp_b, nd1_w, ed1_w,
        en1_w, en1_b, en2_w, en2_b, st1_w, st1_b, st2_w, st2_b, nep_w,
        z_proj, zc, P1, P2, w1T, w2T, out_energy, out_stress);

    edge_table_kernel<<<NB, NB, 0, stream>>>(P1, P2, ed1_b, ed2_w, ed2_b, T4);

    node_edge_kernel<<<NODE_BLOCKS + EDGE_BLOCKS, 256, 0, stream>>>(
        node_emb, graph_id, w1T, nep_b, w2T, nd1_b, nd2_w, nd2_b, zc,
        src, dst, T4, out_node, out_edge);
}